// Round 12
// baseline (242.133 us; speedup 1.0000x reference)
//
#include <hip/hip_runtime.h>
#include <math.h>

#define EPS 1e-8f
#define BS 128
#define W 256
#define N 2048
#define N4 (N / 4)
#define R 4

using v4f = float __attribute__((ext_vector_type(4)));

__device__ inline float wave_sum(float v) {
#pragma unroll
    for (int o = 32; o > 0; o >>= 1) v += __shfl_xor(v, o, 64);
    return v;
}
__device__ inline float wave_max(float v) {
#pragma unroll
    for (int o = 32; o > 0; o >>= 1) v = fmaxf(v, __shfl_xor(v, o, 64));
    return v;
}
__device__ inline float block_sum(float v, volatile float* red, int lane, int wid) {
    v = wave_sum(v);
    if (lane == 0) red[wid] = v;
    __syncthreads();
    v = red[0] + red[1] + red[2] + red[3];
    __syncthreads();
    return v;
}
__device__ inline float block_max(float v, volatile float* red, int lane, int wid) {
    v = wave_max(v);
    if (lane == 0) red[wid] = v;
    __syncthreads();
    v = fmaxf(fmaxf(red[0], red[1]), fmaxf(red[2], red[3]));
    __syncthreads();
    return v;
}
__device__ inline void fma4s(float4& a, float s, const float4& v) {
    a.x += s * v.x; a.y += s * v.y; a.z += s * v.z; a.w += s * v.w;
}
__device__ inline void fma44(float4& a, const float4& u, const float4& v) {
    a.x += u.x * v.x; a.y += u.y * v.y; a.z += u.z * v.z; a.w += u.w * v.w;
}

// ---------------------------------------------------------------------------
// Kernel 1: per-batch prep. block = 256 (= W), grid = BS.
// Outputs: wm, er, knw, knr (ws) + c0[r] = sum_w knr_r*wm, pw = sum_w wm^2.
// ---------------------------------------------------------------------------
__global__ void k_prep(const float* __restrict__ k_r, const float* __restrict__ m_t,
                       const float* __restrict__ e_t, const float* __restrict__ m_er,
                       const float* __restrict__ gW, const float* __restrict__ gb,
                       const float* __restrict__ oW, const float* __restrict__ ob,
                       float* __restrict__ wm_o, float* __restrict__ er_o,
                       float* __restrict__ knw_o, float* __restrict__ knr_o,
                       float* __restrict__ c0_o) {
    int b = blockIdx.x, t = threadIdx.x;
    int lane = t & 63, wid = t >> 6;
    __shared__ float red[4];
    __shared__ float gated[2 * W];
    __shared__ float wk_s[W];

    float wm = tanhf(m_t[b * W + t]);
    float me = m_er[b * W + t];
    wm_o[b * W + t] = wm;

    // erase softmax over W
    float e = e_t[b * W + t];
    float mx = block_max(e, red, lane, wid);
    float ex = expf(e - mx);
    float s = block_sum(ex, red, lane, wid);
    er_o[b * W + t] = ex / s;

    // pw
    float pw = block_sum(wm * wm, red, lane, wid);
    if (t == 0) c0_o[b * 5 + 4] = pw;

    // MixGate scalar g
    float p = wm * gW[t] + me * gW[W + t];
    float ps = block_sum(p, red, lane, wid) + gb[0];
    float g = 1.0f / (1.0f + expf(-ps));
    gated[t] = g * wm;
    gated[W + t] = (1.0f - g) * me;
    __syncthreads();

    // write_key: wave wid computes rows o = wid*64 + i (coalesced float4)
    const float4* g4 = (const float4*)gated;
    float4 g0 = g4[lane];
    float4 g1 = g4[64 + lane];
    for (int i = 0; i < 64; i++) {
        int o = wid * 64 + i;
        const float4* orow = (const float4*)(oW + (size_t)o * 2 * W);
        float4 w0 = orow[lane];
        float4 w1 = orow[64 + lane];
        float pp = w0.x * g0.x + w0.y * g0.y + w0.z * g0.z + w0.w * g0.w
                 + w1.x * g1.x + w1.y * g1.y + w1.z * g1.z + w1.w * g1.w;
        pp = wave_sum(pp);
        if (lane == 0) wk_s[o] = fmaxf(pp + ob[o], 0.0f);
    }
    __syncthreads();
    float wk = wk_s[t];
    float ss = block_sum(wk * wk, red, lane, wid);
    knw_o[b * W + t] = wk / (sqrtf(ss) + EPS);

    // normalized read keys + c0r
    for (int r = 0; r < R; r++) {
        float rk = tanhf(k_r[(b * R + r) * W + t]);
        float s2 = block_sum(rk * rk, red, lane, wid);
        float kn = rk / (sqrtf(s2) + EPS);
        knr_o[(b * R + r) * W + t] = kn;
        float c0 = block_sum(kn * wm, red, lane, wid);
        if (t == 0) c0_o[b * 5 + r] = c0;
    }
}

// ---------------------------------------------------------------------------
// Kernel 2 (pass 1): 14 per-column moments of mem.
// grid (4, BS), block 256; (half = t>>7, c = t&127), n4 = bx*128+c.
// kinds: 0 s1=K.v  1 q0=v.v  2 q1=e.v.v  3 q2=e2.v.v  4 p0=m.v  5 p1=m.e.v
//        6..9 t0r=kr.v   10..13 t1r=kr.e.v
// ---------------------------------------------------------------------------
__global__ void __launch_bounds__(256, 2)
k_moments(const float* __restrict__ mem, const float* __restrict__ knw_g,
          const float* __restrict__ er_g, const float* __restrict__ wm_g,
          const float* __restrict__ knr_g, float4* __restrict__ scr) {
    int b = blockIdx.y, bx = blockIdx.x;
    int t = threadIdx.x;
    int half = t >> 7, c = t & 127;
    int n4 = bx * 128 + c;
    __shared__ float knw_s[W], er_s[W], wm_s[W], knr_s[R * W];
    __shared__ float4 comb[128 * 7];  // 14 KB

    knw_s[t] = knw_g[b * W + t];
    er_s[t]  = er_g[b * W + t];
    wm_s[t]  = wm_g[b * W + t];
#pragma unroll
    for (int r = 0; r < R; r++) knr_s[r * W + t] = knr_g[(b * R + r) * W + t];
    __syncthreads();

    float4 acc[14];
#pragma unroll
    for (int j = 0; j < 14; j++) acc[j] = make_float4(0.f, 0.f, 0.f, 0.f);

    const float4* base = (const float4*)(mem + (size_t)b * W * N) + n4;
    int w0 = half * 128;
    for (int ii = 0; ii < 16; ii++) {
        float4 v[8];
#pragma unroll
        for (int j = 0; j < 8; j++) v[j] = base[(size_t)(w0 + ii * 8 + j) * N4];
#pragma unroll
        for (int j = 0; j < 8; j++) {
            int w = w0 + ii * 8 + j;
            float e = er_s[w], m = wm_s[w], kw = knw_s[w];
            float4 ev;
            ev.x = e * v[j].x; ev.y = e * v[j].y; ev.z = e * v[j].z; ev.w = e * v[j].w;
            fma4s(acc[0], kw, v[j]);
            fma44(acc[1], v[j], v[j]);
            fma44(acc[2], ev, v[j]);
            fma44(acc[3], ev, ev);
            fma4s(acc[4], m, v[j]);
            fma4s(acc[5], m, ev);
            fma4s(acc[6], knr_s[w], v[j]);
            fma4s(acc[7], knr_s[W + w], v[j]);
            fma4s(acc[8], knr_s[2 * W + w], v[j]);
            fma4s(acc[9], knr_s[3 * W + w], v[j]);
            fma4s(acc[10], knr_s[w], ev);
            fma4s(acc[11], knr_s[W + w], ev);
            fma4s(acc[12], knr_s[2 * W + w], ev);
            fma4s(acc[13], knr_s[3 * W + w], ev);
        }
    }

    // cross-half combine in two rounds of 7
    if (half == 0) {
#pragma unroll
        for (int j = 0; j < 7; j++) comb[c * 7 + j] = acc[j];
    }
    __syncthreads();
    if (half == 1) {
#pragma unroll
        for (int j = 0; j < 7; j++) {
            float4 q = comb[c * 7 + j];
            q.x += acc[j].x; q.y += acc[j].y; q.z += acc[j].z; q.w += acc[j].w;
            scr[((size_t)(b * 14 + j)) * N4 + n4] = q;
        }
    }
    __syncthreads();
    if (half == 0) {
#pragma unroll
        for (int j = 0; j < 7; j++) comb[c * 7 + j] = acc[7 + j];
    }
    __syncthreads();
    if (half == 1) {
#pragma unroll
        for (int j = 0; j < 7; j++) {
            float4 q = comb[c * 7 + j];
            q.x += acc[7 + j].x; q.y += acc[7 + j].y; q.z += acc[7 + j].z; q.w += acc[7 + j].w;
            scr[((size_t)(b * 14 + 7 + j)) * N4 + n4] = q;
        }
    }
}

// ---------------------------------------------------------------------------
// Kernel 3 (pass 2): write-softmax -> wwt; dist_r from moments; read-softmax
// -> rwt (output) + C[r]. grid (2, BS), block 256.
// ---------------------------------------------------------------------------
__global__ void k_weights(const float4* __restrict__ scr, const float* __restrict__ c0_g,
                          float* __restrict__ wwt_g, float* __restrict__ rwt_out,
                          float* __restrict__ C_g) {
    int b = blockIdx.y, pair = blockIdx.x;
    int t = threadIdx.x;
    int lane = t & 63, wid = t >> 6;
    __shared__ float red[4];

    const float4* S0 = scr + (size_t)(b * 14) * N4;
    float4 s1a = S0[t],        ssa = S0[N4 + t];
    float4 s1b = S0[256 + t],  ssb = S0[N4 + 256 + t];

    // write-direction dist (negated cosine)
    float4 da, db;
    da.x = -(s1a.x / (sqrtf(ssa.x) + EPS)); da.y = -(s1a.y / (sqrtf(ssa.y) + EPS));
    da.z = -(s1a.z / (sqrtf(ssa.z) + EPS)); da.w = -(s1a.w / (sqrtf(ssa.w) + EPS));
    db.x = -(s1b.x / (sqrtf(ssb.x) + EPS)); db.y = -(s1b.y / (sqrtf(ssb.y) + EPS));
    db.z = -(s1b.z / (sqrtf(ssb.z) + EPS)); db.w = -(s1b.w / (sqrtf(ssb.w) + EPS));

    float m8 = fmaxf(fmaxf(fmaxf(da.x, da.y), fmaxf(da.z, da.w)),
                     fmaxf(fmaxf(db.x, db.y), fmaxf(db.z, db.w)));
    float mx = block_max(m8, red, lane, wid);
    float4 ea, eb;
    ea.x = expf(da.x - mx); ea.y = expf(da.y - mx); ea.z = expf(da.z - mx); ea.w = expf(da.w - mx);
    eb.x = expf(db.x - mx); eb.y = expf(db.y - mx); eb.z = expf(db.z - mx); eb.w = expf(db.w - mx);
    float s8 = ea.x + ea.y + ea.z + ea.w + eb.x + eb.y + eb.z + eb.w;
    float Z = block_sum(s8, red, lane, wid);
    float inv = 1.0f / Z;
    float4 ua, ub;
    ua.x = ea.x * inv; ua.y = ea.y * inv; ua.z = ea.z * inv; ua.w = ea.w * inv;
    ub.x = eb.x * inv; ub.y = eb.y * inv; ub.z = eb.z * inv; ub.w = eb.w * inv;
    if (pair == 0) {
        ((float4*)(wwt_g + (size_t)b * N))[t] = ua;
        ((float4*)(wwt_g + (size_t)b * N))[256 + t] = ub;
    }

    // denominator^2 = q0 + u*(2p0-2q1) + u^2*(q2-2p1+pw)
    float4 q1a = S0[2 * N4 + t], q2a = S0[3 * N4 + t], p0a = S0[4 * N4 + t], p1a = S0[5 * N4 + t];
    float4 q1b = S0[2 * N4 + 256 + t], q2b = S0[3 * N4 + 256 + t],
           p0b = S0[4 * N4 + 256 + t], p1b = S0[5 * N4 + 256 + t];
    float pw = c0_g[b * 5 + 4];

    float4 dena, denb;
    dena.x = sqrtf(ssa.x + ua.x * (2.f * p0a.x - 2.f * q1a.x) + ua.x * ua.x * (q2a.x - 2.f * p1a.x + pw)) + EPS;
    dena.y = sqrtf(ssa.y + ua.y * (2.f * p0a.y - 2.f * q1a.y) + ua.y * ua.y * (q2a.y - 2.f * p1a.y + pw)) + EPS;
    dena.z = sqrtf(ssa.z + ua.z * (2.f * p0a.z - 2.f * q1a.z) + ua.z * ua.z * (q2a.z - 2.f * p1a.z + pw)) + EPS;
    dena.w = sqrtf(ssa.w + ua.w * (2.f * p0a.w - 2.f * q1a.w) + ua.w * ua.w * (q2a.w - 2.f * p1a.w + pw)) + EPS;
    denb.x = sqrtf(ssb.x + ub.x * (2.f * p0b.x - 2.f * q1b.x) + ub.x * ub.x * (q2b.x - 2.f * p1b.x + pw)) + EPS;
    denb.y = sqrtf(ssb.y + ub.y * (2.f * p0b.y - 2.f * q1b.y) + ub.y * ub.y * (q2b.y - 2.f * p1b.y + pw)) + EPS;
    denb.z = sqrtf(ssb.z + ub.z * (2.f * p0b.z - 2.f * q1b.z) + ub.z * ub.z * (q2b.z - 2.f * p1b.z + pw)) + EPS;
    denb.w = sqrtf(ssb.w + ub.w * (2.f * p0b.w - 2.f * q1b.w) + ub.w * ub.w * (q2b.w - 2.f * p1b.w + pw)) + EPS;

#pragma unroll
    for (int rr = 0; rr < 2; rr++) {
        int r = pair * 2 + rr;
        float c0 = c0_g[b * 5 + r];
        float4 t0a = S0[(6 + r) * N4 + t], t1a = S0[(10 + r) * N4 + t];
        float4 t0b = S0[(6 + r) * N4 + 256 + t], t1b = S0[(10 + r) * N4 + 256 + t];
        float4 dra, drb;
        dra.x = (t0a.x + ua.x * (c0 - t1a.x)) / dena.x;
        dra.y = (t0a.y + ua.y * (c0 - t1a.y)) / dena.y;
        dra.z = (t0a.z + ua.z * (c0 - t1a.z)) / dena.z;
        dra.w = (t0a.w + ua.w * (c0 - t1a.w)) / dena.w;
        drb.x = (t0b.x + ub.x * (c0 - t1b.x)) / denb.x;
        drb.y = (t0b.y + ub.y * (c0 - t1b.y)) / denb.y;
        drb.z = (t0b.z + ub.z * (c0 - t1b.z)) / denb.z;
        drb.w = (t0b.w + ub.w * (c0 - t1b.w)) / denb.w;

        float rm = fmaxf(fmaxf(fmaxf(dra.x, dra.y), fmaxf(dra.z, dra.w)),
                         fmaxf(fmaxf(drb.x, drb.y), fmaxf(drb.z, drb.w)));
        float rmx = block_max(rm, red, lane, wid);
        float4 ra, rb;
        ra.x = expf(dra.x - rmx); ra.y = expf(dra.y - rmx);
        ra.z = expf(dra.z - rmx); ra.w = expf(dra.w - rmx);
        rb.x = expf(drb.x - rmx); rb.y = expf(drb.y - rmx);
        rb.z = expf(drb.z - rmx); rb.w = expf(drb.w - rmx);
        float rs = ra.x + ra.y + ra.z + ra.w + rb.x + rb.y + rb.z + rb.w;
        float RZ = block_sum(rs, red, lane, wid);
        float rinv = 1.0f / RZ;
        ra.x *= rinv; ra.y *= rinv; ra.z *= rinv; ra.w *= rinv;
        rb.x *= rinv; rb.y *= rinv; rb.z *= rinv; rb.w *= rinv;
        float4* ro = (float4*)(rwt_out + (size_t)b * R * N);
        ro[r * 512 + t] = ra;
        ro[r * 512 + 256 + t] = rb;
        float cpart = ra.x * ua.x + ra.y * ua.y + ra.z * ua.z + ra.w * ua.w
                    + rb.x * ub.x + rb.y * ub.y + rb.z * ub.z + rb.w * ub.w;
        float C = block_sum(cpart, red, lane, wid);
        if (t == 0) C_g[b * R + r] = C;
    }
}

// ---------------------------------------------------------------------------
// Kernel 4 (pass 3): fused Mnew write + rank-1 m_read. (round-8 body,
// forward b order). SINGLE DIFF vs round 8: plain temporal stores for Mnew
// (L2 write-back pacing) instead of nontemporal.
// ---------------------------------------------------------------------------
__global__ void __launch_bounds__(256, 2)
k_mnew_read(const float* __restrict__ mem, const float* __restrict__ wwt_g,
            const float* __restrict__ rwt_g, const float* __restrict__ C_g,
            const float* __restrict__ er_g, const float* __restrict__ wm_g,
            float* __restrict__ Mnew, float* __restrict__ m_read) {
    int b = blockIdx.y;
    int w0 = blockIdx.x * 64;
    int t = threadIdx.x;
    int lane = t & 63, wid = t >> 6;

    __shared__ float4 rwt4[R * 512];  // 32 KB
    __shared__ float4 wwt4[512];      // 8 KB
    __shared__ float er_s[64], wm_s[64];
    __shared__ float part_a[64][2][4], part_b[64][2][4];

    const float4* ro = (const float4*)(rwt_g + (size_t)b * R * N);
#pragma unroll
    for (int i = 0; i < 8; i++) rwt4[i * 256 + t] = ro[i * 256 + t];
    const float4* wo = (const float4*)(wwt_g + (size_t)b * N);
    wwt4[t] = wo[t];
    wwt4[256 + t] = wo[256 + t];
    if (t < 64) {
        er_s[t] = er_g[b * W + w0 + t];
        wm_s[t] = wm_g[b * W + w0 + t];
    }
    __syncthreads();

    int half = wid & 1, rowgrp = wid >> 1;
    int fbase = half * 256 + lane;

    float4 wt4[4], rw[R][4], uw[R][4];
#pragma unroll
    for (int k = 0; k < 4; k++) wt4[k] = wwt4[fbase + k * 64];
#pragma unroll
    for (int r = 0; r < R; r++)
#pragma unroll
        for (int k = 0; k < 4; k++) {
            rw[r][k] = rwt4[r * 512 + fbase + k * 64];
            uw[r][k].x = rw[r][k].x * wt4[k].x;
            uw[r][k].y = rw[r][k].y * wt4[k].y;
            uw[r][k].z = rw[r][k].z * wt4[k].z;
            uw[r][k].w = rw[r][k].w * wt4[k].w;
        }

    const float* Mb = mem + (size_t)b * W * N;
    float* Ob = Mnew + (size_t)b * W * N;
#pragma unroll 2
    for (int wi = 0; wi < 32; wi++) {
        int wl = rowgrp * 32 + wi;
        float erw = er_s[wl], wmw = wm_s[wl];
        const float4* mrow = (const float4*)(Mb + (size_t)(w0 + wl) * N);
        float4* orow = (float4*)(Ob + (size_t)(w0 + wl) * N);
        float4 v[4];
#pragma unroll
        for (int k = 0; k < 4; k++) v[k] = mrow[fbase + k * 64];
        float a0 = 0.f, a1 = 0.f, a2 = 0.f, a3 = 0.f;
        float b0 = 0.f, b1 = 0.f, b2 = 0.f, b3 = 0.f;
#pragma unroll
        for (int k = 0; k < 4; k++) {
            float4 mn;
            mn.x = v[k].x + wt4[k].x * (wmw - v[k].x * erw);
            mn.y = v[k].y + wt4[k].y * (wmw - v[k].y * erw);
            mn.z = v[k].z + wt4[k].z * (wmw - v[k].z * erw);
            mn.w = v[k].w + wt4[k].w * (wmw - v[k].w * erw);
            orow[fbase + k * 64] = mn;  // plain temporal store (diff vs r8)
            a0 += rw[0][k].x * v[k].x + rw[0][k].y * v[k].y + rw[0][k].z * v[k].z + rw[0][k].w * v[k].w;
            a1 += rw[1][k].x * v[k].x + rw[1][k].y * v[k].y + rw[1][k].z * v[k].z + rw[1][k].w * v[k].w;
            a2 += rw[2][k].x * v[k].x + rw[2][k].y * v[k].y + rw[2][k].z * v[k].z + rw[2][k].w * v[k].w;
            a3 += rw[3][k].x * v[k].x + rw[3][k].y * v[k].y + rw[3][k].z * v[k].z + rw[3][k].w * v[k].w;
            b0 += uw[0][k].x * v[k].x + uw[0][k].y * v[k].y + uw[0][k].z * v[k].z + uw[0][k].w * v[k].w;
            b1 += uw[1][k].x * v[k].x + uw[1][k].y * v[k].y + uw[1][k].z * v[k].z + uw[1][k].w * v[k].w;
            b2 += uw[2][k].x * v[k].x + uw[2][k].y * v[k].y + uw[2][k].z * v[k].z + uw[2][k].w * v[k].w;
            b3 += uw[3][k].x * v[k].x + uw[3][k].y * v[k].y + uw[3][k].z * v[k].z + uw[3][k].w * v[k].w;
        }
        a0 = wave_sum(a0); a1 = wave_sum(a1); a2 = wave_sum(a2); a3 = wave_sum(a3);
        b0 = wave_sum(b0); b1 = wave_sum(b1); b2 = wave_sum(b2); b3 = wave_sum(b3);
        if (lane == 0) {
            part_a[wl][half][0] = a0; part_a[wl][half][1] = a1;
            part_a[wl][half][2] = a2; part_a[wl][half][3] = a3;
            part_b[wl][half][0] = b0; part_b[wl][half][1] = b1;
            part_b[wl][half][2] = b2; part_b[wl][half][3] = b3;
        }
    }
    __syncthreads();
    int w = t >> 2, r = t & 3;
    float A = part_a[w][0][r] + part_a[w][1][r];
    float B = part_b[w][0][r] + part_b[w][1][r];
    float C = C_g[b * R + r];
    float erv = er_s[w];
    float wmv = wm_s[w];
    m_read[((size_t)b * R + r) * W + w0 + w] = A - erv * B + wmv * C;
}

extern "C" void kernel_launch(void* const* d_in, const int* in_sizes, int n_in,
                              void* d_out, int out_size, void* d_ws, size_t ws_size,
                              hipStream_t stream) {
    const float* k_r  = (const float*)d_in[0];
    const float* m_t  = (const float*)d_in[1];
    const float* e_t  = (const float*)d_in[2];
    const float* m_er = (const float*)d_in[3];
    const float* mem  = (const float*)d_in[4];
    const float* gW   = (const float*)d_in[5];
    const float* gb   = (const float*)d_in[6];
    const float* oW   = (const float*)d_in[7];
    const float* ob   = (const float*)d_in[8];

    float* out = (float*)d_out;
    // output layout: m_read (bs,R,W) | M_new (bs,W,N) | read_wt (bs,R,N)
    float* m_read = out;
    float* Mnew   = out + (size_t)BS * R * W;
    float* rwt    = out + (size_t)BS * R * W + (size_t)BS * W * N;

    float* ws  = (float*)d_ws;
    float* wm  = ws;                                   // BS*W
    float* er  = wm + (size_t)BS * W;                  // BS*W
    float* knw = er + (size_t)BS * W;                  // BS*W
    float* knr = knw + (size_t)BS * W;                 // BS*R*W
    float* c0  = knr + (size_t)BS * R * W;             // BS*5 (pad 8)
    float* wwt = c0 + (size_t)BS * 8;                  // BS*N
    float* Cg  = wwt + (size_t)BS * N;                 // BS*R (pad 8)
    float4* scr = (float4*)(Cg + (size_t)BS * 8);      // BS*14*N4 float4

    k_prep<<<BS, 256, 0, stream>>>(k_r, m_t, e_t, m_er, gW, gb, oW, ob,
                                   wm, er, knw, knr, c0);
    k_moments<<<dim3(4, BS), 256, 0, stream>>>(mem, knw, er, wm, knr, scr);
    k_weights<<<dim3(2, BS), 256, 0, stream>>>(scr, c0, wwt, rwt, Cg);
    k_mnew_read<<<dim3(4, BS), 256, 0, stream>>>(mem, wwt, rwt, Cg, er, wm,
                                                 Mnew, m_read);
}

// Round 13
// 207.769 us; speedup vs baseline: 1.1654x; 1.1654x over previous
//
#include <hip/hip_runtime.h>
#include <math.h>

#define EPS 1e-8f
#define BS 128
#define W 256
#define N 2048
#define N4 (N / 4)
#define R 4

using v4f = float __attribute__((ext_vector_type(4)));

__device__ inline float wave_sum(float v) {
#pragma unroll
    for (int o = 32; o > 0; o >>= 1) v += __shfl_xor(v, o, 64);
    return v;
}
__device__ inline float wave_max(float v) {
#pragma unroll
    for (int o = 32; o > 0; o >>= 1) v = fmaxf(v, __shfl_xor(v, o, 64));
    return v;
}
__device__ inline float block_sum(float v, volatile float* red, int lane, int wid) {
    v = wave_sum(v);
    if (lane == 0) red[wid] = v;
    __syncthreads();
    v = red[0] + red[1] + red[2] + red[3];
    __syncthreads();
    return v;
}
__device__ inline float block_max(float v, volatile float* red, int lane, int wid) {
    v = wave_max(v);
    if (lane == 0) red[wid] = v;
    __syncthreads();
    v = fmaxf(fmaxf(red[0], red[1]), fmaxf(red[2], red[3]));
    __syncthreads();
    return v;
}
__device__ inline void fma4s(float4& a, float s, const float4& v) {
    a.x += s * v.x; a.y += s * v.y; a.z += s * v.z; a.w += s * v.w;
}
__device__ inline void fma44(float4& a, const float4& u, const float4& v) {
    a.x += u.x * v.x; a.y += u.y * v.y; a.z += u.z * v.z; a.w += u.w * v.w;
}

// ---------------------------------------------------------------------------
// Kernel 1: per-batch prep. block = 256 (= W), grid = BS.
// Outputs: wm, er, knw, knr (ws) + c0[r] = sum_w knr_r*wm, pw = sum_w wm^2.
// ---------------------------------------------------------------------------
__global__ void k_prep(const float* __restrict__ k_r, const float* __restrict__ m_t,
                       const float* __restrict__ e_t, const float* __restrict__ m_er,
                       const float* __restrict__ gW, const float* __restrict__ gb,
                       const float* __restrict__ oW, const float* __restrict__ ob,
                       float* __restrict__ wm_o, float* __restrict__ er_o,
                       float* __restrict__ knw_o, float* __restrict__ knr_o,
                       float* __restrict__ c0_o) {
    int b = blockIdx.x, t = threadIdx.x;
    int lane = t & 63, wid = t >> 6;
    __shared__ float red[4];
    __shared__ float gated[2 * W];
    __shared__ float wk_s[W];

    float wm = tanhf(m_t[b * W + t]);
    float me = m_er[b * W + t];
    wm_o[b * W + t] = wm;

    // erase softmax over W
    float e = e_t[b * W + t];
    float mx = block_max(e, red, lane, wid);
    float ex = expf(e - mx);
    float s = block_sum(ex, red, lane, wid);
    er_o[b * W + t] = ex / s;

    // pw
    float pw = block_sum(wm * wm, red, lane, wid);
    if (t == 0) c0_o[b * 5 + 4] = pw;

    // MixGate scalar g
    float p = wm * gW[t] + me * gW[W + t];
    float ps = block_sum(p, red, lane, wid) + gb[0];
    float g = 1.0f / (1.0f + expf(-ps));
    gated[t] = g * wm;
    gated[W + t] = (1.0f - g) * me;
    __syncthreads();

    // write_key: wave wid computes rows o = wid*64 + i (coalesced float4)
    const float4* g4 = (const float4*)gated;
    float4 g0 = g4[lane];
    float4 g1 = g4[64 + lane];
    for (int i = 0; i < 64; i++) {
        int o = wid * 64 + i;
        const float4* orow = (const float4*)(oW + (size_t)o * 2 * W);
        float4 w0 = orow[lane];
        float4 w1 = orow[64 + lane];
        float pp = w0.x * g0.x + w0.y * g0.y + w0.z * g0.z + w0.w * g0.w
                 + w1.x * g1.x + w1.y * g1.y + w1.z * g1.z + w1.w * g1.w;
        pp = wave_sum(pp);
        if (lane == 0) wk_s[o] = fmaxf(pp + ob[o], 0.0f);
    }
    __syncthreads();
    float wk = wk_s[t];
    float ss = block_sum(wk * wk, red, lane, wid);
    knw_o[b * W + t] = wk / (sqrtf(ss) + EPS);

    // normalized read keys + c0r
    for (int r = 0; r < R; r++) {
        float rk = tanhf(k_r[(b * R + r) * W + t]);
        float s2 = block_sum(rk * rk, red, lane, wid);
        float kn = rk / (sqrtf(s2) + EPS);
        knr_o[(b * R + r) * W + t] = kn;
        float c0 = block_sum(kn * wm, red, lane, wid);
        if (t == 0) c0_o[b * 5 + r] = c0;
    }
}

// ---------------------------------------------------------------------------
// Kernel 2 (pass 1): 14 per-column moments of mem.
// grid (4, BS), block 256; (half = t>>7, c = t&127), n4 = bx*128+c.
// kinds: 0 s1=K.v  1 q0=v.v  2 q1=e.v.v  3 q2=e2.v.v  4 p0=m.v  5 p1=m.e.v
//        6..9 t0r=kr.v   10..13 t1r=kr.e.v
// Scratch layout: scr[(b*14+kind)*N4 + n4] (float4).
// ---------------------------------------------------------------------------
__global__ void __launch_bounds__(256, 2)
k_moments(const float* __restrict__ mem, const float* __restrict__ knw_g,
          const float* __restrict__ er_g, const float* __restrict__ wm_g,
          const float* __restrict__ knr_g, float4* __restrict__ scr) {
    int b = blockIdx.y, bx = blockIdx.x;
    int t = threadIdx.x;
    int half = t >> 7, c = t & 127;
    int n4 = bx * 128 + c;
    __shared__ float knw_s[W], er_s[W], wm_s[W], knr_s[R * W];
    __shared__ float4 comb[128 * 7];  // 14 KB

    knw_s[t] = knw_g[b * W + t];
    er_s[t]  = er_g[b * W + t];
    wm_s[t]  = wm_g[b * W + t];
#pragma unroll
    for (int r = 0; r < R; r++) knr_s[r * W + t] = knr_g[(b * R + r) * W + t];
    __syncthreads();

    float4 acc[14];
#pragma unroll
    for (int j = 0; j < 14; j++) acc[j] = make_float4(0.f, 0.f, 0.f, 0.f);

    const float4* base = (const float4*)(mem + (size_t)b * W * N) + n4;
    int w0 = half * 128;
#pragma unroll 4
    for (int i = 0; i < 128; i++) {
        int w = w0 + i;
        float4 v = base[(size_t)w * N4];
        float e = er_s[w], m = wm_s[w], kw = knw_s[w];
        float4 ev;
        ev.x = e * v.x; ev.y = e * v.y; ev.z = e * v.z; ev.w = e * v.w;
        fma4s(acc[0], kw, v);
        fma44(acc[1], v, v);
        fma44(acc[2], ev, v);
        fma44(acc[3], ev, ev);
        fma4s(acc[4], m, v);
        fma4s(acc[5], m, ev);
        fma4s(acc[6], knr_s[w], v);
        fma4s(acc[7], knr_s[W + w], v);
        fma4s(acc[8], knr_s[2 * W + w], v);
        fma4s(acc[9], knr_s[3 * W + w], v);
        fma4s(acc[10], knr_s[w], ev);
        fma4s(acc[11], knr_s[W + w], ev);
        fma4s(acc[12], knr_s[2 * W + w], ev);
        fma4s(acc[13], knr_s[3 * W + w], ev);
    }

    // cross-half combine in two rounds of 7
    if (half == 0) {
#pragma unroll
        for (int j = 0; j < 7; j++) comb[c * 7 + j] = acc[j];
    }
    __syncthreads();
    if (half == 1) {
#pragma unroll
        for (int j = 0; j < 7; j++) {
            float4 q = comb[c * 7 + j];
            q.x += acc[j].x; q.y += acc[j].y; q.z += acc[j].z; q.w += acc[j].w;
            scr[((size_t)(b * 14 + j)) * N4 + n4] = q;
        }
    }
    __syncthreads();
    if (half == 0) {
#pragma unroll
        for (int j = 0; j < 7; j++) comb[c * 7 + j] = acc[7 + j];
    }
    __syncthreads();
    if (half == 1) {
#pragma unroll
        for (int j = 0; j < 7; j++) {
            float4 q = comb[c * 7 + j];
            q.x += acc[7 + j].x; q.y += acc[7 + j].y; q.z += acc[7 + j].z; q.w += acc[7 + j].w;
            scr[((size_t)(b * 14 + 7 + j)) * N4 + n4] = q;
        }
    }
}

// ---------------------------------------------------------------------------
// Kernel 3 (pass 2): write-softmax -> wwt; dist_r from moments; read-softmax
// -> rwt (output) + C[r]. grid (2, BS), block 256; pair = blockIdx.x handles
// r in {2*pair, 2*pair+1}.
// ---------------------------------------------------------------------------
__global__ void k_weights(const float4* __restrict__ scr, const float* __restrict__ c0_g,
                          float* __restrict__ wwt_g, float* __restrict__ rwt_out,
                          float* __restrict__ C_g) {
    int b = blockIdx.y, pair = blockIdx.x;
    int t = threadIdx.x;
    int lane = t & 63, wid = t >> 6;
    __shared__ float red[4];

    const float4* S0 = scr + (size_t)(b * 14) * N4;
    float4 s1a = S0[t],        ssa = S0[N4 + t];
    float4 s1b = S0[256 + t],  ssb = S0[N4 + 256 + t];

    // write-direction dist (negated cosine)
    float4 da, db;
    da.x = -(s1a.x / (sqrtf(ssa.x) + EPS)); da.y = -(s1a.y / (sqrtf(ssa.y) + EPS));
    da.z = -(s1a.z / (sqrtf(ssa.z) + EPS)); da.w = -(s1a.w / (sqrtf(ssa.w) + EPS));
    db.x = -(s1b.x / (sqrtf(ssb.x) + EPS)); db.y = -(s1b.y / (sqrtf(ssb.y) + EPS));
    db.z = -(s1b.z / (sqrtf(ssb.z) + EPS)); db.w = -(s1b.w / (sqrtf(ssb.w) + EPS));

    float m8 = fmaxf(fmaxf(fmaxf(da.x, da.y), fmaxf(da.z, da.w)),
                     fmaxf(fmaxf(db.x, db.y), fmaxf(db.z, db.w)));
    float mx = block_max(m8, red, lane, wid);
    float4 ea, eb;
    ea.x = expf(da.x - mx); ea.y = expf(da.y - mx); ea.z = expf(da.z - mx); ea.w = expf(da.w - mx);
    eb.x = expf(db.x - mx); eb.y = expf(db.y - mx); eb.z = expf(db.z - mx); eb.w = expf(db.w - mx);
    float s8 = ea.x + ea.y + ea.z + ea.w + eb.x + eb.y + eb.z + eb.w;
    float Z = block_sum(s8, red, lane, wid);
    float inv = 1.0f / Z;
    float4 ua, ub;
    ua.x = ea.x * inv; ua.y = ea.y * inv; ua.z = ea.z * inv; ua.w = ea.w * inv;
    ub.x = eb.x * inv; ub.y = eb.y * inv; ub.z = eb.z * inv; ub.w = eb.w * inv;
    if (pair == 0) {
        ((float4*)(wwt_g + (size_t)b * N))[t] = ua;
        ((float4*)(wwt_g + (size_t)b * N))[256 + t] = ub;
    }

    // denominator^2 = q0 + u*(2p0-2q1) + u^2*(q2-2p1+pw)
    float4 q1a = S0[2 * N4 + t], q2a = S0[3 * N4 + t], p0a = S0[4 * N4 + t], p1a = S0[5 * N4 + t];
    float4 q1b = S0[2 * N4 + 256 + t], q2b = S0[3 * N4 + 256 + t],
           p0b = S0[4 * N4 + 256 + t], p1b = S0[5 * N4 + 256 + t];
    float pw = c0_g[b * 5 + 4];

    float4 dena, denb;
    dena.x = sqrtf(ssa.x + ua.x * (2.f * p0a.x - 2.f * q1a.x) + ua.x * ua.x * (q2a.x - 2.f * p1a.x + pw)) + EPS;
    dena.y = sqrtf(ssa.y + ua.y * (2.f * p0a.y - 2.f * q1a.y) + ua.y * ua.y * (q2a.y - 2.f * p1a.y + pw)) + EPS;
    dena.z = sqrtf(ssa.z + ua.z * (2.f * p0a.z - 2.f * q1a.z) + ua.z * ua.z * (q2a.z - 2.f * p1a.z + pw)) + EPS;
    dena.w = sqrtf(ssa.w + ua.w * (2.f * p0a.w - 2.f * q1a.w) + ua.w * ua.w * (q2a.w - 2.f * p1a.w + pw)) + EPS;
    denb.x = sqrtf(ssb.x + ub.x * (2.f * p0b.x - 2.f * q1b.x) + ub.x * ub.x * (q2b.x - 2.f * p1b.x + pw)) + EPS;
    denb.y = sqrtf(ssb.y + ub.y * (2.f * p0b.y - 2.f * q1b.y) + ub.y * ub.y * (q2b.y - 2.f * p1b.y + pw)) + EPS;
    denb.z = sqrtf(ssb.z + ub.z * (2.f * p0b.z - 2.f * q1b.z) + ub.z * ub.z * (q2b.z - 2.f * p1b.z + pw)) + EPS;
    denb.w = sqrtf(ssb.w + ub.w * (2.f * p0b.w - 2.f * q1b.w) + ub.w * ub.w * (q2b.w - 2.f * p1b.w + pw)) + EPS;

#pragma unroll
    for (int rr = 0; rr < 2; rr++) {
        int r = pair * 2 + rr;
        float c0 = c0_g[b * 5 + r];
        float4 t0a = S0[(6 + r) * N4 + t], t1a = S0[(10 + r) * N4 + t];
        float4 t0b = S0[(6 + r) * N4 + 256 + t], t1b = S0[(10 + r) * N4 + 256 + t];
        float4 dra, drb;
        dra.x = (t0a.x + ua.x * (c0 - t1a.x)) / dena.x;
        dra.y = (t0a.y + ua.y * (c0 - t1a.y)) / dena.y;
        dra.z = (t0a.z + ua.z * (c0 - t1a.z)) / dena.z;
        dra.w = (t0a.w + ua.w * (c0 - t1a.w)) / dena.w;
        drb.x = (t0b.x + ub.x * (c0 - t1b.x)) / denb.x;
        drb.y = (t0b.y + ub.y * (c0 - t1b.y)) / denb.y;
        drb.z = (t0b.z + ub.z * (c0 - t1b.z)) / denb.z;
        drb.w = (t0b.w + ub.w * (c0 - t1b.w)) / denb.w;

        float rm = fmaxf(fmaxf(fmaxf(dra.x, dra.y), fmaxf(dra.z, dra.w)),
                         fmaxf(fmaxf(drb.x, drb.y), fmaxf(drb.z, drb.w)));
        float rmx = block_max(rm, red, lane, wid);
        float4 ra, rb;
        ra.x = expf(dra.x - rmx); ra.y = expf(dra.y - rmx);
        ra.z = expf(dra.z - rmx); ra.w = expf(dra.w - rmx);
        rb.x = expf(drb.x - rmx); rb.y = expf(drb.y - rmx);
        rb.z = expf(drb.z - rmx); rb.w = expf(drb.w - rmx);
        float rs = ra.x + ra.y + ra.z + ra.w + rb.x + rb.y + rb.z + rb.w;
        float RZ = block_sum(rs, red, lane, wid);
        float rinv = 1.0f / RZ;
        ra.x *= rinv; ra.y *= rinv; ra.z *= rinv; ra.w *= rinv;
        rb.x *= rinv; rb.y *= rinv; rb.z *= rinv; rb.w *= rinv;
        float4* ro = (float4*)(rwt_out + (size_t)b * R * N);
        ro[r * 512 + t] = ra;
        ro[r * 512 + 256 + t] = rb;
        float cpart = ra.x * ua.x + ra.y * ua.y + ra.z * ua.z + ra.w * ua.w
                    + rb.x * ub.x + rb.y * ub.y + rb.z * ub.z + rb.w * ub.w;
        float C = block_sum(cpart, red, lane, wid);
        if (t == 0) C_g[b * R + r] = C;
    }
}

// ---------------------------------------------------------------------------
// Kernel 4 (pass 3): fused Mnew write + rank-1 m_read.
// grid (4, BS), block 256 (4 waves), w-tile 64. Wave (rowgrp=wid>>1,
// half=wid&1): rows rowgrp*32..+32, n in half*1024..+1024 (fbase slots).
// Mnew NT-stored (confirmed: temporal stores cost +34 µs); A,B accumulated
// vs mem; m_read = A - er*B + wm*C.  [best-known config, round 8]
// ---------------------------------------------------------------------------
__global__ void __launch_bounds__(256, 2)
k_mnew_read(const float* __restrict__ mem, const float* __restrict__ wwt_g,
            const float* __restrict__ rwt_g, const float* __restrict__ C_g,
            const float* __restrict__ er_g, const float* __restrict__ wm_g,
            float* __restrict__ Mnew, float* __restrict__ m_read) {
    int b = blockIdx.y;
    int w0 = blockIdx.x * 64;
    int t = threadIdx.x;
    int lane = t & 63, wid = t >> 6;

    __shared__ float4 rwt4[R * 512];  // 32 KB
    __shared__ float4 wwt4[512];      // 8 KB
    __shared__ float er_s[64], wm_s[64];
    __shared__ float part_a[64][2][4], part_b[64][2][4];

    const float4* ro = (const float4*)(rwt_g + (size_t)b * R * N);
#pragma unroll
    for (int i = 0; i < 8; i++) rwt4[i * 256 + t] = ro[i * 256 + t];
    const float4* wo = (const float4*)(wwt_g + (size_t)b * N);
    wwt4[t] = wo[t];
    wwt4[256 + t] = wo[256 + t];
    if (t < 64) {
        er_s[t] = er_g[b * W + w0 + t];
        wm_s[t] = wm_g[b * W + w0 + t];
    }
    __syncthreads();

    int half = wid & 1, rowgrp = wid >> 1;
    int fbase = half * 256 + lane;

    float4 wt4[4], rw[R][4], uw[R][4];
#pragma unroll
    for (int k = 0; k < 4; k++) wt4[k] = wwt4[fbase + k * 64];
#pragma unroll
    for (int r = 0; r < R; r++)
#pragma unroll
        for (int k = 0; k < 4; k++) {
            rw[r][k] = rwt4[r * 512 + fbase + k * 64];
            uw[r][k].x = rw[r][k].x * wt4[k].x;
            uw[r][k].y = rw[r][k].y * wt4[k].y;
            uw[r][k].z = rw[r][k].z * wt4[k].z;
            uw[r][k].w = rw[r][k].w * wt4[k].w;
        }

    const float* Mb = mem + (size_t)b * W * N;
    float* Ob = Mnew + (size_t)b * W * N;
#pragma unroll 2
    for (int wi = 0; wi < 32; wi++) {
        int wl = rowgrp * 32 + wi;
        float erw = er_s[wl], wmw = wm_s[wl];
        const float4* mrow = (const float4*)(Mb + (size_t)(w0 + wl) * N);
        v4f* orow = (v4f*)(Ob + (size_t)(w0 + wl) * N);
        float4 v[4];
#pragma unroll
        for (int k = 0; k < 4; k++) v[k] = mrow[fbase + k * 64];
        float a0 = 0.f, a1 = 0.f, a2 = 0.f, a3 = 0.f;
        float b0 = 0.f, b1 = 0.f, b2 = 0.f, b3 = 0.f;
#pragma unroll
        for (int k = 0; k < 4; k++) {
            v4f mn;
            mn[0] = v[k].x + wt4[k].x * (wmw - v[k].x * erw);
            mn[1] = v[k].y + wt4[k].y * (wmw - v[k].y * erw);
            mn[2] = v[k].z + wt4[k].z * (wmw - v[k].z * erw);
            mn[3] = v[k].w + wt4[k].w * (wmw - v[k].w * erw);
            __builtin_nontemporal_store(mn, orow + fbase + k * 64);
            a0 += rw[0][k].x * v[k].x + rw[0][k].y * v[k].y + rw[0][k].z * v[k].z + rw[0][k].w * v[k].w;
            a1 += rw[1][k].x * v[k].x + rw[1][k].y * v[k].y + rw[1][k].z * v[k].z + rw[1][k].w * v[k].w;
            a2 += rw[2][k].x * v[k].x + rw[2][k].y * v[k].y + rw[2][k].z * v[k].z + rw[2][k].w * v[k].w;
            a3 += rw[3][k].x * v[k].x + rw[3][k].y * v[k].y + rw[3][k].z * v[k].z + rw[3][k].w * v[k].w;
            b0 += uw[0][k].x * v[k].x + uw[0][k].y * v[k].y + uw[0][k].z * v[k].z + uw[0][k].w * v[k].w;
            b1 += uw[1][k].x * v[k].x + uw[1][k].y * v[k].y + uw[1][k].z * v[k].z + uw[1][k].w * v[k].w;
            b2 += uw[2][k].x * v[k].x + uw[2][k].y * v[k].y + uw[2][k].z * v[k].z + uw[2][k].w * v[k].w;
            b3 += uw[3][k].x * v[k].x + uw[3][k].y * v[k].y + uw[3][k].z * v[k].z + uw[3][k].w * v[k].w;
        }
        a0 = wave_sum(a0); a1 = wave_sum(a1); a2 = wave_sum(a2); a3 = wave_sum(a3);
        b0 = wave_sum(b0); b1 = wave_sum(b1); b2 = wave_sum(b2); b3 = wave_sum(b3);
        if (lane == 0) {
            part_a[wl][half][0] = a0; part_a[wl][half][1] = a1;
            part_a[wl][half][2] = a2; part_a[wl][half][3] = a3;
            part_b[wl][half][0] = b0; part_b[wl][half][1] = b1;
            part_b[wl][half][2] = b2; part_b[wl][half][3] = b3;
        }
    }
    __syncthreads();
    int w = t >> 2, r = t & 3;
    float A = part_a[w][0][r] + part_a[w][1][r];
    float B = part_b[w][0][r] + part_b[w][1][r];
    float C = C_g[b * R + r];
    float erv = er_s[w];
    float wmv = wm_s[w];
    m_read[((size_t)b * R + r) * W + w0 + w] = A - erv * B + wmv * C;
}

extern "C" void kernel_launch(void* const* d_in, const int* in_sizes, int n_in,
                              void* d_out, int out_size, void* d_ws, size_t ws_size,
                              hipStream_t stream) {
    const float* k_r  = (const float*)d_in[0];
    const float* m_t  = (const float*)d_in[1];
    const float* e_t  = (const float*)d_in[2];
    const float* m_er = (const float*)d_in[3];
    const float* mem  = (const float*)d_in[4];
    const float* gW   = (const float*)d_in[5];
    const float* gb   = (const float*)d_in[6];
    const float* oW   = (const float*)d_in[7];
    const float* ob   = (const float*)d_in[8];

    float* out = (float*)d_out;
    // output layout: m_read (bs,R,W) | M_new (bs,W,N) | read_wt (bs,R,N)
    float* m_read = out;
    float* Mnew   = out + (size_t)BS * R * W;
    float* rwt    = out + (size_t)BS * R * W + (size_t)BS * W * N;

    float* ws  = (float*)d_ws;
    float* wm  = ws;                                   // BS*W
    float* er  = wm + (size_t)BS * W;                  // BS*W
    float* knw = er + (size_t)BS * W;                  // BS*W
    float* knr = knw + (size_t)BS * W;                 // BS*R*W
    float* c0  = knr + (size_t)BS * R * W;             // BS*5 (pad 8)
    float* wwt = c0 + (size_t)BS * 8;                  // BS*N
    float* Cg  = wwt + (size_t)BS * N;                 // BS*R (pad 8)
    float4* scr = (float4*)(Cg + (size_t)BS * 8);      // BS*14*N4 float4

    k_prep<<<BS, 256, 0, stream>>>(k_r, m_t, e_t, m_er, gW, gb, oW, ob,
                                   wm, er, knw, knr, c0);
    k_moments<<<dim3(4, BS), 256, 0, stream>>>(mem, knw, er, wm, knr, scr);
    k_weights<<<dim3(2, BS), 256, 0, stream>>>(scr, c0, wwt, rwt, Cg);
    k_mnew_read<<<dim3(4, BS), 256, 0, stream>>>(mem, wwt, rwt, Cg, er, wm,
                                                 Mnew, m_read);
}